// Round 11
// baseline (105.130 us; speedup 1.0000x reference)
//
#include <hip/hip_runtime.h>
#include <hip/hip_cooperative_groups.h>

namespace cg = cooperative_groups;

#define NN    16384
#define CBN   64
#define SUBV  16
#define KCODE 16
#define DOUTN 1024
#define DEP   4

typedef short bf16x8 __attribute__((ext_vector_type(8)));
typedef float f32x16 __attribute__((ext_vector_type(16)));

static __device__ __forceinline__ unsigned short f2bf(float f) {
  unsigned int u = __float_as_uint(f);
  u += 0x7FFFu + ((u >> 16) & 1u);   // RNE; inputs are normal randn, no NaN/Inf
  return (unsigned short)(u >> 16);
}

// global -> LDS direct copy, 16B/lane. LDS dest wave-uniform (HW adds lane*16).
static __device__ __forceinline__ void gld16(const void* g, void* l) {
  __builtin_amdgcn_global_load_lds(
      (const __attribute__((address_space(1))) unsigned int*)g,
      (__attribute__((address_space(3))) unsigned int*)(uintptr_t)l, 16, 0, 0);
}

// ---------------- kernel 1: table convert + swizzle (R7 code, 64 blocks) ----
__global__ __launch_bounds__(256) void convert_k(
    const float* __restrict__ Tg, unsigned int* __restrict__ Tswz) {
  const int t = threadIdx.x;
  const int img = blockIdx.x;                   // = g8*8 + ch
  const int g = img >> 3, ch = img & 7;
  unsigned int* dst = Tswz + (size_t)img * 8192; // 8192 u32 = 32 KiB image
  const int colq = t & 31, kp = (t >> 5) & 7;
  #pragma unroll
  for (int cl = 0; cl < 8; ++cl) {
    const float* g0 = Tg + ((size_t)((ch * 8 + cl) * KCODE + 2 * kp)) * DOUTN
                      + g * 128 + colq * 4;
    float4 r0 = *(const float4*)g0;             // k=2kp   (coalesced)
    float4 r1 = *(const float4*)(g0 + DOUTN);   // k=2kp+1
    unsigned int pk[4] = {
      f2bf(r0.x) | ((unsigned int)f2bf(r1.x) << 16),
      f2bf(r0.y) | ((unsigned int)f2bf(r1.y) << 16),
      f2bf(r0.z) | ((unsigned int)f2bf(r1.z) << 16),
      f2bf(r0.w) | ((unsigned int)f2bf(r1.w) << 16)};
    unsigned key = (unsigned)(colq & 7) << 2;   // XOR on u32-idx bits[4:2]
    #pragma unroll
    for (int j = 0; j < 4; ++j)
      dst[cl * 1024 + ((((unsigned)(colq * 4 + j)) * 8 + (unsigned)kp) ^ key)]
          = pk[j];
  }
}

// ---------------- kernel 2: cooperative fused encode + MFMA ----------------
// 256 blocks x 1024 thr = 1 block/CU (coop). Block b: colgroup g16 = b&15,
// compute rowgroup rg = b>>4; ENCODES rows b*64..+64 (blocks rg*16..+15
// together produce exactly rowgroup rg -> grid.sync makes them visible).
// Order: (1) issue gld16 stage of the colgroup image (drains under encode);
// (2) split tables -> LDS; (3) direct-line encode: a subvec = exactly one
// 64-B line, so 4 hoisted independent scalar loads/row fetch each line once
// (no xs staging, no per-pass barriers); svalT is [d][e][c] -> bank = c&31,
// conflict-free; (4) grid.sync; (5) R7 compute loop + single epilogue.
__global__ __launch_bounds__(1024, 4) void fused_k(
    const float* __restrict__ x, const int* __restrict__ split_idxs,
    const float* __restrict__ split_vals, const unsigned int* __restrict__ Tswz,
    const float* __restrict__ bias, unsigned char* __restrict__ codes,
    float* __restrict__ out) {
  __shared__ __align__(16) unsigned int Tb[32768];   // 128 KiB: [ch8][cl8][512 u32]
  __shared__ int   sidxT[DEP * CBN];                 // [d][c]
  __shared__ float svalT[DEP * (KCODE / 2) * CBN];   // [d][e][c]

  const int t = threadIdx.x;
  const int b = blockIdx.x;
  const int g16 = b & 15;
  const int n0 = (b >> 4) * 1024;
  const int wid = t >> 6, lane = t & 63, lrow = lane & 31, h = lane >> 5;

  // (1) stage colgroup image: 128 segs of 1024 B; wave stages 8 (R7 map)
  {
    const int g8 = g16 >> 1, half = g16 & 1;
    const char* img = (const char*)Tswz + (size_t)g8 * 8 * 32768;
    #pragma unroll
    for (int i = 0; i < 8; ++i) {
      int gs = wid * 8 + i;
      int ch = gs >> 4, s16 = gs & 15, cl = s16 >> 1, pc = s16 & 1;
      gld16(img + ch * 32768 + cl * 4096 + half * 2048 + pc * 1024 + lane * 16,
            (char*)Tb + gs * 1024);
    }
  }

  // (2) split tables -> LDS
  if (t < DEP * CBN) {
    int d = t >> 6, c = t & 63;
    sidxT[t] = split_idxs[c * DEP + d];
  }
  for (int i = t; i < DEP * (KCODE / 2) * CBN; i += 1024) {
    int c = i & 63, de = i >> 6, d = de >> 3, e = de & 7;
    svalT[i] = split_vals[(c * DEP + d) * (KCODE / 2) + e];
  }
  __syncthreads();                 // splits ready (also drains gld16 - ~1us, ok)

  // (3) encode own 64 rows: wave wid -> rows b*64 + wid*4 .. +4, lane = c
  {
    const int c = lane;
    const size_t r0 = (size_t)b * 64 + wid * 4;
    const float* xr = x + r0 * DOUTN + c * SUBV;
    const int si0 = sidxT[c], si1 = sidxT[64 + c],
              si2 = sidxT[128 + c], si3 = sidxT[192 + c];
    float xv[4][4];
    #pragma unroll
    for (int i = 0; i < 4; ++i) {               // 16 independent loads, 1 line/(row,c)
      const float* xri = xr + (size_t)i * DOUTN;
      xv[i][0] = xri[si0]; xv[i][1] = xri[si1];
      xv[i][2] = xri[si2]; xv[i][3] = xri[si3];
    }
    #pragma unroll
    for (int i = 0; i < 4; ++i) {
      int e = 0;
      #pragma unroll
      for (int d = 0; d < DEP; ++d) {
        float th = svalT[(d * 8 + e) * 64 + c];
        e = 2 * e + (xv[i][d] > th ? 1 : 0);
      }
      codes[(r0 + i) * CBN + c] = (unsigned char)e;
    }
  }

  cg::this_grid().sync();                        // codes + Tb ready grid-wide

  // (5) compute: R7 loop verbatim (stagger, JIT bv[2], A per rt)
  f32x16 acc[2][2];
  #pragma unroll
  for (int rt = 0; rt < 2; ++rt)
    #pragma unroll
    for (int ct = 0; ct < 2; ++ct)
      #pragma unroll
      for (int e = 0; e < 16; ++e) acc[rt][ct][e] = 0.f;

  const unsigned char* crow0 = codes + (size_t)(n0 + wid * 64 + lrow) * CBN;
  const unsigned char* crow1 = crow0 + 32 * CBN;

  #pragma unroll
  for (int i = 0; i < 8; ++i) {
    const int ch = (wid + i) & 7;                // per-wave stagger
    const unsigned long long qw0 = *(const unsigned long long*)(crow0 + ch * 8);
    const unsigned long long qw1 = *(const unsigned long long*)(crow1 + ch * 8);
    const unsigned short* tbc = (const unsigned short*)Tb + ch * 8192;
    #pragma unroll
    for (int cl = 0; cl < 8; ++cl) {
      bf16x8 bv[2];
      #pragma unroll
      for (int ct = 0; ct < 2; ++ct) {
        unsigned col_loc = (unsigned)(ct * 32 + lrow);
        unsigned uidx = (unsigned)(cl * 1024)
                      + ((col_loc * 16 + (unsigned)h * 8)
                         ^ (((col_loc >> 2) & 7u) << 3));
        bv[ct] = *(const bf16x8*)(tbc + uidx);
      }
      #pragma unroll
      for (int rt = 0; rt < 2; ++rt) {
        int c = (int)(((rt ? qw1 : qw0) >> (8 * cl)) & 255);
        int p = c >> 1;
        unsigned s = 0x3F80u << ((c & 1) << 4);  // bf16(1.0) in right half
        union { unsigned int u[4]; bf16x8 v; } A;
        #pragma unroll
        for (int j = 0; j < 4; ++j) A.u[j] = (p == h * 4 + j) ? s : 0u;
        acc[rt][0] = __builtin_amdgcn_mfma_f32_32x32x16_bf16(A.v, bv[0], acc[rt][0], 0, 0, 0);
        acc[rt][1] = __builtin_amdgcn_mfma_f32_32x32x16_bf16(A.v, bv[1], acc[rt][1], 0, 0, 0);
      }
    }
  }

  // single epilogue: D layout col=lane&31, row=(reg&3)+8*(reg>>2)+4*(lane>>5)
  #pragma unroll
  for (int ct = 0; ct < 2; ++ct) {
    const int col = g16 * 64 + ct * 32 + lrow;
    const float bval = bias[col];
    #pragma unroll
    for (int rt = 0; rt < 2; ++rt)
      #pragma unroll
      for (int r = 0; r < 16; ++r) {
        int row = n0 + wid * 64 + rt * 32 + (r & 3) + 8 * (r >> 2) + 4 * h;
        out[(size_t)row * DOUTN + col] = acc[rt][ct][r] + bval;
      }
  }
}

extern "C" void kernel_launch(void* const* d_in, const int* in_sizes, int n_in,
                              void* d_out, int out_size, void* d_ws, size_t ws_size,
                              hipStream_t stream) {
  const float* x    = (const float*)d_in[0];
  const int*   sidx = (const int*)d_in[1];
  const float* sval = (const float*)d_in[2];
  const float* Tg   = (const float*)d_in[3];
  const float* bias = (const float*)d_in[4];
  float* out = (float*)d_out;
  unsigned char* codes = (unsigned char*)d_ws;                       // 1 MiB
  unsigned int*  Tswz  = (unsigned int*)((char*)d_ws + (1 << 20));   // 2 MiB

  convert_k<<<64, 256, 0, stream>>>(Tg, Tswz);
  const unsigned int* TswzC = Tswz;
  void* args[] = {(void*)&x, (void*)&sidx, (void*)&sval, (void*)&TswzC,
                  (void*)&bias, (void*)&codes, (void*)&out};
  hipLaunchCooperativeKernel((const void*)fused_k, dim3(256), dim3(1024),
                             args, 0, stream);
}

// Round 12
// 59.481 us; speedup vs baseline: 1.7675x; 1.7675x over previous
//
#include <hip/hip_runtime.h>

#define NN    16384
#define CBN   64
#define SUBV  16
#define KCODE 16
#define DOUTN 1024
#define DEP   4

typedef short bf16x8 __attribute__((ext_vector_type(8)));
typedef float f32x16 __attribute__((ext_vector_type(16)));

static __device__ __forceinline__ unsigned short f2bf(float f) {
  unsigned int u = __float_as_uint(f);
  u += 0x7FFFu + ((u >> 16) & 1u);   // RNE; inputs are normal randn, no NaN/Inf
  return (unsigned short)(u >> 16);
}

// global -> LDS direct copy, 16B/lane. LDS dest wave-uniform (HW adds lane*16).
static __device__ __forceinline__ void gld16(const void* g, void* l) {
  __builtin_amdgcn_global_load_lds(
      (const __attribute__((address_space(1))) unsigned int*)g,
      (__attribute__((address_space(3))) unsigned int*)(uintptr_t)l, 16, 0, 0);
}

// ---------------- kernel 1: table convert/swizzle + encode (R10, proven) ----
// blocks [0,64): build Tswz (bf16, pre-swizzled 32 KiB images) — first, so
// they overlap encode. blocks [64, 64+2048): encode 8 rows -> codes[n][c] u8.
__global__ __launch_bounds__(256) void prep_k(
    const float* __restrict__ x, const int* __restrict__ split_idxs,
    const float* __restrict__ split_vals, const float* __restrict__ Tg,
    unsigned char* __restrict__ codes, unsigned int* __restrict__ Tswz) {
  const int t = threadIdx.x;

  if (blockIdx.x < 64) {
    const int img = blockIdx.x;                   // = g8*8 + ch
    const int g = img >> 3, ch = img & 7;
    unsigned int* dst = Tswz + (size_t)img * 8192; // 8192 u32 = 32 KiB image
    const int colq = t & 31, kp = (t >> 5) & 7;
    #pragma unroll
    for (int cl = 0; cl < 8; ++cl) {
      const float* g0 = Tg + ((size_t)((ch * 8 + cl) * KCODE + 2 * kp)) * DOUTN
                        + g * 128 + colq * 4;
      float4 r0 = *(const float4*)g0;             // k=2kp   (coalesced)
      float4 r1 = *(const float4*)(g0 + DOUTN);   // k=2kp+1
      unsigned int pk[4] = {
        f2bf(r0.x) | ((unsigned int)f2bf(r1.x) << 16),
        f2bf(r0.y) | ((unsigned int)f2bf(r1.y) << 16),
        f2bf(r0.z) | ((unsigned int)f2bf(r1.z) << 16),
        f2bf(r0.w) | ((unsigned int)f2bf(r1.w) << 16)};
      unsigned key = (unsigned)(colq & 7) << 2;   // XOR on u32-idx bits[4:2]
      #pragma unroll
      for (int j = 0; j < 4; ++j)
        dst[cl * 1024 + ((((unsigned)(colq * 4 + j)) * 8 + (unsigned)kp) ^ key)]
            = pk[j];
    }
    return;
  }

  // ---- encode ----
  __shared__ __align__(16) float xs[8][SUBV * CBN];
  __shared__ int   sidxT[DEP * CBN];               // [d][c]
  __shared__ float svalT[DEP * (KCODE / 2) * CBN]; // [d][e][c]
  if (t < DEP * CBN) {
    int d = t >> 6, c = t & 63;
    sidxT[t] = split_idxs[c * DEP + d];
  }
  for (int i = t; i < DEP * (KCODE / 2) * CBN; i += 256) {
    int c = i & 63, de = i >> 6, d = de >> 3, e = de & 7;
    svalT[i] = split_vals[(c * DEP + d) * (KCODE / 2) + e];
  }
  const int n0 = (blockIdx.x - 64) * 8;
  const float4* xg = (const float4*)(x + (size_t)n0 * DOUTN);
  #pragma unroll
  for (int i = 0; i < 8; ++i) {                    // 8 rows * 256 float4/row
    int li = t + i * 256;
    int r = li >> 8, cpos = li & 255;
    float4 v = xg[r * 256 + cpos];
    int c = cpos >> 2, q = cpos & 3;
    *(float4*)&xs[r][c * SUBV + ((q ^ (c & 3)) << 2)] = v;
  }
  __syncthreads();
  const int c = t & 63, rg = t >> 6;
  #pragma unroll
  for (int i = 0; i < 2; ++i) {
    int nl = rg * 2 + i;
    int e = 0;
    #pragma unroll
    for (int d = 0; d < DEP; ++d) {
      int si = sidxT[d * 64 + c];
      float xv = xs[nl][c * SUBV + (((si >> 2) ^ (c & 3)) << 2) + (si & 3)];
      float th = svalT[(d * 8 + e) * 64 + c];
      e = 2 * e + (xv > th ? 1 : 0);
    }
    codes[(size_t)(n0 + nl) * CBN + c] = (unsigned char)e;
  }
}

// ---------------- kernel 2: one-hot MFMA gather-accumulate ----------------
// grid (16 colgroups, 16 rowgroups) = 256 blocks = 1/CU; 1024 thr = 16 waves.
// R10 shell (gld16 one-shot 128 KiB stage, ONE barrier, free-run, stagger,
// single epilogue). NEW wave shape: 128 rows x 32 cols (rt=4, ct=1; wid ->
// rq=wid>>1 row-block, cq=wid&1 col-half). Rationale (R9/R11 counters): LDS
// pipe (24.6K read cyc + 11.3K conflict cyc/CU) was ABOVE the 33K-cyc MFMA
// pipe and they serialize per-wave; ct=1 gives 1 b128-read : 4 MFMA, halving
// LDS bytes+conflicts (-> ~18K cyc, safely under MFMA). VALU doubles to
// ~25K cyc/SIMD-sum — still under. R5 precedent: this shape writes exactly
// 64 MiB (no R9 split-write penalty).
__global__ __launch_bounds__(1024, 4) void maddness_mfma(
    const unsigned int* __restrict__ Tswz, const float* __restrict__ bias,
    const unsigned char* __restrict__ codes, float* __restrict__ out) {
  __shared__ __align__(16) unsigned int Tb[32768];   // 128 KiB: [ch8][cl8][512 u32]

  const int t = threadIdx.x;
  const int wid = t >> 6, lane = t & 63, lrow = lane & 31, h = lane >> 5;
  const int rq = wid >> 1, cq = wid & 1;
  const int g16 = blockIdx.x, g8 = g16 >> 1, half = g16 & 1;
  const int n0 = blockIdx.y * 1024;
  const char* img = (const char*)Tswz + (size_t)g8 * 8 * 32768;

  // stage all 8 chunk half-images: 128 segs of 1024 B; wave stages 8 (R7 map)
  #pragma unroll
  for (int i = 0; i < 8; ++i) {
    int gs = wid * 8 + i;
    int ch = gs >> 4, s16 = gs & 15, cl = s16 >> 1, pc = s16 & 1;
    gld16(img + ch * 32768 + cl * 4096 + half * 2048 + pc * 1024 + lane * 16,
          (char*)Tb + gs * 1024);
  }

  f32x16 acc[4];
  #pragma unroll
  for (int rt = 0; rt < 4; ++rt)
    #pragma unroll
    for (int e = 0; e < 16; ++e) acc[rt][e] = 0.f;

  // 4 row-tiles: rows n0 + rq*128 + rt*32 + lrow
  const unsigned char* crow = codes + (size_t)(n0 + rq * 128 + lrow) * CBN;

  // B-read address (ct fixed = cq): within-cl u16 idx, XOR swizzle
  const unsigned col_loc = (unsigned)(cq * 32 + lrow);
  const unsigned rb = (col_loc * 16 + (unsigned)h * 8)
                    ^ (((col_loc >> 2) & 7u) << 3);
  const unsigned short* tb0 = (const unsigned short*)Tb + rb;

  __syncthreads();                                  // the ONLY barrier

  #pragma unroll
  for (int i = 0; i < 8; ++i) {
    const int ch = (wid + i) & 7;                   // per-wave stagger
    unsigned long long qw[4];
    #pragma unroll
    for (int rt = 0; rt < 4; ++rt)
      qw[rt] = *(const unsigned long long*)(crow + (size_t)rt * 32 * CBN + ch * 8);
    const unsigned short* tbc = tb0 + ch * 8192;
    #pragma unroll
    for (int cl = 0; cl < 8; ++cl) {
      const bf16x8 bv = *(const bf16x8*)(tbc + cl * 1024);  // 1 read : 4 MFMA
      #pragma unroll
      for (int rt = 0; rt < 4; ++rt) {
        int c = (int)((qw[rt] >> (8 * cl)) & 255);
        int p = c >> 1;
        unsigned s = 0x3F80u << ((c & 1) << 4);     // bf16(1.0) in right half
        union { unsigned int u[4]; bf16x8 v; } A;
        #pragma unroll
        for (int j = 0; j < 4; ++j) A.u[j] = (p == h * 4 + j) ? s : 0u;
        acc[rt] = __builtin_amdgcn_mfma_f32_32x32x16_bf16(A.v, bv, acc[rt], 0, 0, 0);
      }
    }
  }

  // single epilogue: D layout col=lane&31, row=(reg&3)+8*(reg>>2)+4*(lane>>5)
  const int col = g16 * 64 + cq * 32 + lrow;
  const float bval = bias[col];
  #pragma unroll
  for (int rt = 0; rt < 4; ++rt)
    #pragma unroll
    for (int r = 0; r < 16; ++r) {
      int row = n0 + rq * 128 + rt * 32 + (r & 3) + 8 * (r >> 2) + 4 * h;
      out[(size_t)row * DOUTN + col] = acc[rt][r] + bval;
    }
}

extern "C" void kernel_launch(void* const* d_in, const int* in_sizes, int n_in,
                              void* d_out, int out_size, void* d_ws, size_t ws_size,
                              hipStream_t stream) {
  const float* x    = (const float*)d_in[0];
  const int*   sidx = (const int*)d_in[1];
  const float* sval = (const float*)d_in[2];
  const float* Tg   = (const float*)d_in[3];
  const float* bias = (const float*)d_in[4];
  float* out = (float*)d_out;
  unsigned char* codes = (unsigned char*)d_ws;                       // 1 MiB
  unsigned int*  Tswz  = (unsigned int*)((char*)d_ws + (1 << 20));   // 2 MiB

  prep_k<<<64 + NN / 8, 256, 0, stream>>>(x, sidx, sval, Tg, codes, Tswz);
  maddness_mfma<<<dim3(16, 16), 1024, 0, stream>>>(Tswz, bias, codes, out);
}

// Round 13
// 51.905 us; speedup vs baseline: 2.0255x; 1.1460x over previous
//
#include <hip/hip_runtime.h>

#define NN    16384
#define CBN   64
#define SUBV  16
#define KCODE 16
#define DOUTN 1024
#define DEP   4

typedef short bf16x8 __attribute__((ext_vector_type(8)));
typedef float f32x16 __attribute__((ext_vector_type(16)));

static __device__ __forceinline__ unsigned short f2bf(float f) {
  unsigned int u = __float_as_uint(f);
  u += 0x7FFFu + ((u >> 16) & 1u);   // RNE; inputs are normal randn, no NaN/Inf
  return (unsigned short)(u >> 16);
}

// global -> LDS direct copy, 16B/lane. LDS dest wave-uniform (HW adds lane*16).
static __device__ __forceinline__ void gld16(const void* g, void* l) {
  __builtin_amdgcn_global_load_lds(
      (const __attribute__((address_space(1))) unsigned int*)g,
      (__attribute__((address_space(3))) unsigned int*)(uintptr_t)l, 16, 0, 0);
}

// ---------------- kernel 1: table convert/swizzle + encode (R10, proven) ----
__global__ __launch_bounds__(256) void prep_k(
    const float* __restrict__ x, const int* __restrict__ split_idxs,
    const float* __restrict__ split_vals, const float* __restrict__ Tg,
    unsigned char* __restrict__ codes, unsigned int* __restrict__ Tswz) {
  const int t = threadIdx.x;

  if (blockIdx.x < 64) {
    const int img = blockIdx.x;                   // = g8*8 + ch
    const int g = img >> 3, ch = img & 7;
    unsigned int* dst = Tswz + (size_t)img * 8192; // 8192 u32 = 32 KiB image
    const int colq = t & 31, kp = (t >> 5) & 7;
    #pragma unroll
    for (int cl = 0; cl < 8; ++cl) {
      const float* g0 = Tg + ((size_t)((ch * 8 + cl) * KCODE + 2 * kp)) * DOUTN
                        + g * 128 + colq * 4;
      float4 r0 = *(const float4*)g0;             // k=2kp   (coalesced)
      float4 r1 = *(const float4*)(g0 + DOUTN);   // k=2kp+1
      unsigned int pk[4] = {
        f2bf(r0.x) | ((unsigned int)f2bf(r1.x) << 16),
        f2bf(r0.y) | ((unsigned int)f2bf(r1.y) << 16),
        f2bf(r0.z) | ((unsigned int)f2bf(r1.z) << 16),
        f2bf(r0.w) | ((unsigned int)f2bf(r1.w) << 16)};
      unsigned key = (unsigned)(colq & 7) << 2;   // XOR on u32-idx bits[4:2]
      #pragma unroll
      for (int j = 0; j < 4; ++j)
        dst[cl * 1024 + ((((unsigned)(colq * 4 + j)) * 8 + (unsigned)kp) ^ key)]
            = pk[j];
    }
    return;
  }

  // ---- encode ----
  __shared__ __align__(16) float xs[8][SUBV * CBN];
  __shared__ int   sidxT[DEP * CBN];               // [d][c]
  __shared__ float svalT[DEP * (KCODE / 2) * CBN]; // [d][e][c]
  if (t < DEP * CBN) {
    int d = t >> 6, c = t & 63;
    sidxT[t] = split_idxs[c * DEP + d];
  }
  for (int i = t; i < DEP * (KCODE / 2) * CBN; i += 256) {
    int c = i & 63, de = i >> 6, d = de >> 3, e = de & 7;
    svalT[i] = split_vals[(c * DEP + d) * (KCODE / 2) + e];
  }
  const int n0 = (blockIdx.x - 64) * 8;
  const float4* xg = (const float4*)(x + (size_t)n0 * DOUTN);
  #pragma unroll
  for (int i = 0; i < 8; ++i) {                    // 8 rows * 256 float4/row
    int li = t + i * 256;
    int r = li >> 8, cpos = li & 255;
    float4 v = xg[r * 256 + cpos];
    int c = cpos >> 2, q = cpos & 3;
    *(float4*)&xs[r][c * SUBV + ((q ^ (c & 3)) << 2)] = v;
  }
  __syncthreads();
  const int c = t & 63, rg = t >> 6;
  #pragma unroll
  for (int i = 0; i < 2; ++i) {
    int nl = rg * 2 + i;
    int e = 0;
    #pragma unroll
    for (int d = 0; d < DEP; ++d) {
      int si = sidxT[d * 64 + c];
      float xv = xs[nl][c * SUBV + (((si >> 2) ^ (c & 3)) << 2) + (si & 3)];
      float th = svalT[(d * 8 + e) * 64 + c];
      e = 2 * e + (xv > th ? 1 : 0);
    }
    codes[(size_t)(n0 + nl) * CBN + c] = (unsigned char)e;
  }
}

// ---------------- kernel 2: one-hot MFMA gather-accumulate ----------------
// grid (16 colgroups, 16 rowgroups) = 256 blocks = 1/CU; 1024 thr = 16 waves.
// R10 shell (one-shot gld16 stage, ONE barrier, free-run, stagger, single
// epilogue). Shape rt=2 x ct=2 (wave = 64 rows x 64 cols, wr=16): no
// cross-wave A duplication -> 2048 A-builds/CU (half of R12), each feeding
// 2 MFMA. A-build cheapened to ~10 VALU via u64-shift one-hot:
//   frag128 = 0x3F80 << 16*(c&7) gated by (c>>3)==h
//   == q[0] = (c>>2 == 2h) ? 0x3F80<<((c&3)*16) : 0 ; q[1] same vs 2h+1.
// One-ahead prefetch of code-u64s (next i) and B-frags (next cl) removes
// per-iter waitcnt stalls (pipes were summing: 13.7 MFMA + 23 VALU + ...).
// Bias folded into acc init (col is lane-constant).
__global__ __launch_bounds__(1024, 4) void maddness_mfma(
    const unsigned int* __restrict__ Tswz, const float* __restrict__ bias,
    const unsigned char* __restrict__ codes, float* __restrict__ out) {
  __shared__ __align__(16) unsigned int Tb[32768];   // 128 KiB: [ch8][cl8][512 u32]

  const int t = threadIdx.x;
  const int wid = t >> 6, lane = t & 63, lrow = lane & 31, h = lane >> 5;
  const int g16 = blockIdx.x, g8 = g16 >> 1, half = g16 & 1;
  const int n0 = blockIdx.y * 1024;
  const char* img = (const char*)Tswz + (size_t)g8 * 8 * 32768;

  // stage all 8 chunk half-images: 128 segs of 1024 B; wave stages 8 (R7 map)
  #pragma unroll
  for (int i = 0; i < 8; ++i) {
    int gs = wid * 8 + i;
    int ch = gs >> 4, s16 = gs & 15, cl = s16 >> 1, pc = s16 & 1;
    gld16(img + ch * 32768 + cl * 4096 + half * 2048 + pc * 1024 + lane * 16,
          (char*)Tb + gs * 1024);
  }

  // bias for this lane's two columns (col = g16*64 + ct*32 + lrow)
  const float bv0 = bias[g16 * 64 + lrow];
  const float bv1 = bias[g16 * 64 + 32 + lrow];

  f32x16 acc[2][2];
  #pragma unroll
  for (int rt = 0; rt < 2; ++rt)
    #pragma unroll
    for (int e = 0; e < 16; ++e) { acc[rt][0][e] = bv0; acc[rt][1][e] = bv1; }

  const unsigned char* crow0 = codes + (size_t)(n0 + wid * 64 + lrow) * CBN;
  const unsigned char* crow1 = crow0 + 32 * CBN;
  const unsigned h2 = 2u * (unsigned)h, h2p = h2 + 1u;
  const unsigned rb0 = ((unsigned)lrow * 16 + (unsigned)h * 8)
                     ^ ((((unsigned)lrow >> 2) & 7u) << 3);
  const unsigned cl32 = (unsigned)lrow + 32u;
  const unsigned rb1 = (cl32 * 16 + (unsigned)h * 8)
                     ^ (((cl32 >> 2) & 7u) << 3);

  __syncthreads();                                  // the ONLY barrier

  // software pipeline heads: codes for i=0, B-frags for (i=0, cl=0)
  const int ch0 = wid & 7;
  unsigned long long qA0 = *(const unsigned long long*)(crow0 + ch0 * 8);
  unsigned long long qA1 = *(const unsigned long long*)(crow1 + ch0 * 8);
  const unsigned short* tbc = (const unsigned short*)Tb + ch0 * 8192;
  bf16x8 bP0 = *(const bf16x8*)(tbc + rb0);
  bf16x8 bP1 = *(const bf16x8*)(tbc + rb1);

  #pragma unroll
  for (int i = 0; i < 8; ++i) {
    const int chn = (wid + i + 1) & 7;
    const unsigned short* tbn = (const unsigned short*)Tb + chn * 8192;
    const unsigned long long q0 = qA0, q1 = qA1;
    if (i < 7) {                                    // prefetch next codes
      qA0 = *(const unsigned long long*)(crow0 + chn * 8);
      qA1 = *(const unsigned long long*)(crow1 + chn * 8);
    }
    #pragma unroll
    for (int cl = 0; cl < 8; ++cl) {
      const bf16x8 b0 = bP0, b1 = bP1;
      if (!(i == 7 && cl == 7)) {                   // prefetch next B-frags
        const unsigned short* tnx = (cl == 7) ? tbn : (tbc + (cl + 1) * 1024);
        bP0 = *(const bf16x8*)(tnx + rb0);
        bP1 = *(const bf16x8*)(tnx + rb1);
      }
      #pragma unroll
      for (int rt = 0; rt < 2; ++rt) {
        const unsigned q32 =
            (unsigned)((rt ? q1 : q0) >> ((cl & 4) ? 32 : 0));
        const unsigned bpos = 8u * (unsigned)(cl & 3);
        const unsigned sh  = (q32 >> bpos) & 3u;        // c & 3
        const unsigned key = (q32 >> (bpos + 2)) & 3u;  // c >> 2
        const unsigned long long tt = 0x3F80ULL << (sh << 4);
        union { unsigned long long q[2]; bf16x8 v; } A;
        A.q[0] = (key == h2)  ? tt : 0ULL;
        A.q[1] = (key == h2p) ? tt : 0ULL;
        acc[rt][0] = __builtin_amdgcn_mfma_f32_32x32x16_bf16(A.v, b0, acc[rt][0], 0, 0, 0);
        acc[rt][1] = __builtin_amdgcn_mfma_f32_32x32x16_bf16(A.v, b1, acc[rt][1], 0, 0, 0);
      }
    }
    tbc = tbn;
  }

  // single epilogue (bias already in acc):
  // D layout col=lane&31, row=(reg&3)+8*(reg>>2)+4*(lane>>5)
  #pragma unroll
  for (int ct = 0; ct < 2; ++ct) {
    const int col = g16 * 64 + ct * 32 + lrow;
    #pragma unroll
    for (int rt = 0; rt < 2; ++rt)
      #pragma unroll
      for (int r = 0; r < 16; ++r) {
        int row = n0 + wid * 64 + rt * 32 + (r & 3) + 8 * (r >> 2) + 4 * h;
        out[(size_t)row * DOUTN + col] = acc[rt][ct][r];
      }
  }
}

extern "C" void kernel_launch(void* const* d_in, const int* in_sizes, int n_in,
                              void* d_out, int out_size, void* d_ws, size_t ws_size,
                              hipStream_t stream) {
  const float* x    = (const float*)d_in[0];
  const int*   sidx = (const int*)d_in[1];
  const float* sval = (const float*)d_in[2];
  const float* Tg   = (const float*)d_in[3];
  const float* bias = (const float*)d_in[4];
  float* out = (float*)d_out;
  unsigned char* codes = (unsigned char*)d_ws;                       // 1 MiB
  unsigned int*  Tswz  = (unsigned int*)((char*)d_ws + (1 << 20));   // 2 MiB

  prep_k<<<64 + NN / 8, 256, 0, stream>>>(x, sidx, sval, Tg, codes, Tswz);
  maddness_mfma<<<dim3(16, 16), 1024, 0, stream>>>(Tswz, bias, codes, out);
}